// Round 6
// baseline (309.889 us; speedup 1.0000x reference)
//
#include <hip/hip_runtime.h>
#include <hip/hip_bf16.h>

#define T_ROWS 8192
#define K_DIM  1024
#define N_DIM  2048
#define G_NUM  8
#define CONVB_BLOCKS 4096   // G*(K/64)*(N/64)

typedef __attribute__((ext_vector_type(8))) short short8;
typedef __attribute__((ext_vector_type(4))) float v4f;

// ---------- helpers ----------
__device__ __forceinline__ unsigned short f2bf(float x) {
  unsigned int u = __builtin_bit_cast(unsigned int, x);
  u += 0x7fffu + ((u >> 16) & 1u);   // round-to-nearest-even
  return (unsigned short)(u >> 16);
}
__device__ __forceinline__ unsigned int pk2(float a, float b) {
  return (unsigned int)f2bf(a) | ((unsigned int)f2bf(b) << 16);
}
__device__ __forceinline__ void async_cp16(const void* gsrc, void* ldst) {
  __builtin_amdgcn_global_load_lds(
      (const __attribute__((address_space(1))) void*)gsrc,
      (__attribute__((address_space(3))) void*)ldst, 16, 0, 0);
}

// ---------- conv: B[g][k][n] fp32 -> Bt[g][n][k] bf16 (padded-LDS transpose) ----
// A's convert is now fused into the GEMM (A fp32 is already K-contiguous).
__global__ __launch_bounds__(256) void conv_b(const float* __restrict__ B,
                                              unsigned short* __restrict__ Bt) {
  __shared__ float tile[64][65];   // +1 pad -> conflict-free
  const int bidx = blockIdx.x;     // [0, 4096)
  const int t = threadIdx.x;
  const int nt = bidx & 31;          // N/64
  const int kt = (bidx >> 5) & 15;   // K/64
  const int g  = bidx >> 9;          // G
  const int c4 = t & 15;
  const int r  = t >> 4;

  const float* src = B + ((size_t)g * K_DIM + (size_t)kt * 64) * N_DIM + (size_t)nt * 64;
#pragma unroll
  for (int i = 0; i < 4; ++i) {
    int k = r + i * 16;
    float4 v = *(const float4*)(src + (size_t)k * N_DIM + c4 * 4);
    tile[k][c4 * 4 + 0] = v.x; tile[k][c4 * 4 + 1] = v.y;
    tile[k][c4 * 4 + 2] = v.z; tile[k][c4 * 4 + 3] = v.w;
  }
  __syncthreads();
  unsigned short* dst = Bt + ((size_t)g * N_DIM + (size_t)nt * 64) * K_DIM + (size_t)kt * 64;
#pragma unroll
  for (int i = 0; i < 2; ++i) {
    int idx = t + i * 256;
    int n = idx >> 3;
    int seg = idx & 7;
    unsigned int u0 = pk2(tile[seg * 8 + 0][n], tile[seg * 8 + 1][n]);
    unsigned int u1 = pk2(tile[seg * 8 + 2][n], tile[seg * 8 + 3][n]);
    unsigned int u2 = pk2(tile[seg * 8 + 4][n], tile[seg * 8 + 5][n]);
    unsigned int u3 = pk2(tile[seg * 8 + 6][n], tile[seg * 8 + 7][n]);
    uint4 o; o.x = u0; o.y = u1; o.z = u2; o.w = u3;
    *(uint4*)(dst + (size_t)n * K_DIM + seg * 8) = o;
  }
}

// ---------- grouped bf16 MFMA GEMM, 128x128 tile, BK=64 ----------
// XCD-swizzled 1152-block grid (8 xcd * 9 contiguous mslots * 16 ntiles):
// FETCH measured at ~ideal 49.5 MB with this mapping (R5).
// A is staged DIRECTLY from fp32 input: float4 reg loads issued at the TOP of
// the k-iter (latency hidden under compute -- something global_load_lds's
// issue-at-end structure cannot express), converted to bf16 and ds_write_b128
// into As after the 2nd barrier with the same XOR swizzle as the read side.
// B comes from the pre-transposed bf16 Btb via global_load_lds (unchanged).
__global__ __launch_bounds__(256) void gemm_kernel(const float* __restrict__ A,
                                                   const unsigned short* __restrict__ Btb,
                                                   const int* __restrict__ offs,
                                                   float* __restrict__ out) {
  __shared__ unsigned short As[128 * 64];
  __shared__ unsigned short Bs[128 * 64];
  const int t = threadIdx.x;

  const int b = blockIdx.x;
  const int xcd = b & 7;
  const int j = b >> 3;              // [0,144)
  const int mslot = xcd * 9 + (j >> 4);
  const int n0 = (j & 15) * 128;

  // slot -> (group, row tile); wave-uniform
  int prev = 0, cum = 0, row0 = 0, row_end = 0, g = 0, found = 0;
#pragma unroll
  for (int gg = 0; gg < G_NUM; ++gg) {
    int e = offs[gg];
    int tiles = (e - prev + 127) >> 7;
    if (!found && mslot < cum + tiles) {
      found = 1; g = gg; row0 = prev + (mslot - cum) * 128; row_end = e;
    }
    cum += tiles;
    prev = e;
  }
  if (!found) return;

  const int lane = t & 63;
  const int wv = t >> 6;
  const int wm = wv & 1;
  const int wn = wv >> 1;
  const int srcChunk = (t & 7) ^ ((t >> 3) & 7);  // XOR swizzle, matches frag-read side

  // A fp32 sources (reg-staged) and swizzled LDS write addresses
  const float* aSrcF[4];
  char* aDstW[4];
  // B bf16 sources (global_load_lds) -- unchanged from R5
  const unsigned short* bSrc[4];
  char* bDst[4];
#pragma unroll
  for (int c = 0; c < 4; ++c) {
    int rl = c * 32 + (t >> 3);
    int rA = row0 + rl; if (rA > T_ROWS - 1) rA = T_ROWS - 1;  // tail clamp (store-masked)
    aSrcF[c] = A + (size_t)rA * K_DIM + (t & 7) * 8;
    aDstW[c] = (char*)As + rl * 128 + srcChunk * 16;   // logical chunk (t&7) at phys (t&7)^(rl&7)
    bSrc[c] = Btb + ((size_t)g * N_DIM + n0 + rl) * K_DIM + srcChunk * 8;
    bDst[c] = (char*)Bs + c * 4096 + t * 16;
  }

  v4f acc[4][4];
#pragma unroll
  for (int i = 0; i < 4; ++i)
#pragma unroll
    for (int j2 = 0; j2 < 4; ++j2)
#pragma unroll
      for (int r = 0; r < 4; ++r) acc[i][j2][r] = 0.0f;

  // prologue: stage k0=0. A: reg load + convert + ds_write; B: async cp.
  float4 af0[4], af1[4];
#pragma unroll
  for (int c = 0; c < 4; ++c) {
    af0[c] = *(const float4*)(aSrcF[c]);
    af1[c] = *(const float4*)(aSrcF[c] + 4);
  }
#pragma unroll
  for (int c = 0; c < 4; ++c) {
    async_cp16(bSrc[c], bDst[c]);
  }
#pragma unroll
  for (int c = 0; c < 4; ++c) {
    uint4 o;
    o.x = pk2(af0[c].x, af0[c].y); o.y = pk2(af0[c].z, af0[c].w);
    o.z = pk2(af1[c].x, af1[c].y); o.w = pk2(af1[c].z, af1[c].w);
    *(uint4*)aDstW[c] = o;
  }

  for (int k0 = 0; k0 < K_DIM; k0 += 64) {
    __syncthreads();   // drains lgkm (A ds_write) + vmcnt (B cp) -> tiles ready
    const bool more = (k0 + 64) < K_DIM;
    if (more) {
      int koff = k0 + 64;
#pragma unroll
      for (int c = 0; c < 4; ++c) {       // next A-tile: latency hides under MFMA below
        af0[c] = *(const float4*)(aSrcF[c] + koff);
        af1[c] = *(const float4*)(aSrcF[c] + koff + 4);
      }
    }
#pragma unroll
    for (int ks = 0; ks < 2; ++ks) {
      short8 a[4], bfr[4];
      int chBase = (lane >> 4) + ks * 4;
      int chPhys = chBase ^ (lane & 7);
#pragma unroll
      for (int im = 0; im < 4; ++im) {
        int row = wm * 64 + im * 16 + (lane & 15);
        a[im] = *(const short8*)((const char*)As + row * 128 + chPhys * 16);
      }
#pragma unroll
      for (int in = 0; in < 4; ++in) {
        int row = wn * 64 + in * 16 + (lane & 15);
        bfr[in] = *(const short8*)((const char*)Bs + row * 128 + chPhys * 16);
      }
#pragma unroll
      for (int im = 0; im < 4; ++im)
#pragma unroll
        for (int in = 0; in < 4; ++in)
          acc[im][in] = __builtin_amdgcn_mfma_f32_16x16x32_bf16(a[im], bfr[in], acc[im][in], 0, 0, 0);
    }
    if (more) {
      __syncthreads();   // all waves done reading LDS
      int koff = k0 + 64;
#pragma unroll
      for (int c = 0; c < 4; ++c) {
        uint4 o;
        o.x = pk2(af0[c].x, af0[c].y); o.y = pk2(af0[c].z, af0[c].w);
        o.z = pk2(af1[c].x, af1[c].y); o.w = pk2(af1[c].z, af1[c].w);
        *(uint4*)aDstW[c] = o;
        async_cp16(bSrc[c] + koff, bDst[c]);
      }
    }
  }

  // epilogue: C/D layout col=lane&15, row=(lane>>4)*4+reg
  const int colBase = n0 + wn * 64 + (lane & 15);
  const int rowBase = row0 + wm * 64 + ((lane >> 4) << 2);
#pragma unroll
  for (int im = 0; im < 4; ++im) {
#pragma unroll
    for (int in = 0; in < 4; ++in) {
      int c = colBase + in * 16;
#pragma unroll
      for (int r = 0; r < 4; ++r) {
        int rr = rowBase + im * 16 + r;
        if (rr < row_end) out[(size_t)rr * N_DIM + c] = acc[im][in][r];
      }
    }
  }
}

// ---------- fallback (workspace too small): fp32 vector GEMM ----------
__global__ __launch_bounds__(256) void fallback_kernel(const float* __restrict__ A,
                                                       const float* __restrict__ B,
                                                       const int* __restrict__ offs,
                                                       float* __restrict__ out) {
  int r = blockIdx.y;
  int c = blockIdx.x * 256 + threadIdx.x;
  int g = 0;
#pragma unroll
  for (int i = 0; i < G_NUM; ++i) g += (offs[i] <= r);
  const float* a = A + (size_t)r * K_DIM;
  const float* b = B + (size_t)g * K_DIM * N_DIM + c;
  float s = 0.f;
  for (int k = 0; k < K_DIM; ++k) s += a[k] * b[(size_t)k * N_DIM];
  out[(size_t)r * N_DIM + c] = s;
}

extern "C" void kernel_launch(void* const* d_in, const int* in_sizes, int n_in,
                              void* d_out, int out_size, void* d_ws, size_t ws_size,
                              hipStream_t stream) {
  const float* A = (const float*)d_in[0];
  const float* B = (const float*)d_in[1];
  const int* offs = (const int*)d_in[2];
  float* out = (float*)d_out;

  size_t need = (size_t)G_NUM * K_DIM * N_DIM * 2;   // Btb only now
  if (ws_size < need) {
    dim3 grid(N_DIM / 256, T_ROWS);
    fallback_kernel<<<grid, 256, 0, stream>>>(A, B, offs, out);
    return;
  }
  unsigned short* Btb = (unsigned short*)d_ws;

  conv_b<<<CONVB_BLOCKS, 256, 0, stream>>>(B, Btb);
  // linear grid, XCD-swizzled inside: 8 * 9 * 16 = 1152 blocks
  gemm_kernel<<<8 * 9 * 16, 256, 0, stream>>>(A, Btb, offs, out);
}